// Round 6
// baseline (233.877 us; speedup 1.0000x reference)
//
#include <hip/hip_runtime.h>
#include <cstddef>

// DCT-II matrix (float32 cast of numpy's float64 values)
static constexpr float D8[8][8] = {
  { 0.35355339059327373f, 0.35355339059327373f, 0.35355339059327373f, 0.35355339059327373f,
    0.35355339059327373f, 0.35355339059327373f, 0.35355339059327373f, 0.35355339059327373f},
  { 0.4903926402016152f,  0.4157348061512726f,  0.27778511650980114f, 0.09754516100806417f,
   -0.09754516100806417f,-0.27778511650980114f,-0.4157348061512726f, -0.4903926402016152f},
  { 0.46193976625564337f, 0.19134171618254492f,-0.19134171618254492f,-0.46193976625564337f,
   -0.46193976625564337f,-0.19134171618254492f, 0.19134171618254492f, 0.46193976625564337f},
  { 0.4157348061512726f, -0.09754516100806417f,-0.4903926402016152f, -0.27778511650980114f,
    0.27778511650980114f, 0.4903926402016152f,  0.09754516100806417f,-0.4157348061512726f},
  { 0.35355339059327373f,-0.35355339059327373f,-0.35355339059327373f, 0.35355339059327373f,
    0.35355339059327373f,-0.35355339059327373f,-0.35355339059327373f, 0.35355339059327373f},
  { 0.27778511650980114f,-0.4903926402016152f,  0.09754516100806417f, 0.4157348061512726f,
   -0.4157348061512726f, -0.09754516100806417f, 0.4903926402016152f, -0.27778511650980114f},
  { 0.19134171618254492f,-0.46193976625564337f, 0.46193976625564337f,-0.19134171618254492f,
   -0.19134171618254492f, 0.46193976625564337f,-0.46193976625564337f, 0.19134171618254492f},
  { 0.09754516100806417f,-0.27778511650980114f, 0.4157348061512726f, -0.4903926402016152f,
    0.4903926402016152f, -0.4157348061512726f,  0.27778511650980114f,-0.09754516100806417f},
};

// Quality-95 quant tables: q = clamp(floor((base*10+50)/100), 1, 255)
static constexpr float QLt[8][8] = {
  {2,1,1,2,2,4,5,6},
  {1,1,1,2,3,6,6,6},
  {1,1,2,2,4,6,7,6},
  {1,2,2,3,5,9,8,6},
  {2,2,4,6,7,11,10,8},
  {2,4,6,6,8,10,11,9},
  {5,6,8,9,10,12,12,10},
  {7,9,10,10,11,10,10,10},
};
static constexpr float QCt[8][8] = {
  {2,2,2,5,10,10,10,10},
  {2,2,3,7,10,10,10,10},
  {2,3,6,10,10,10,10,10},
  {5,7,10,10,10,10,10,10},
  {10,10,10,10,10,10,10,10},
  {10,10,10,10,10,10,10,10},
  {10,10,10,10,10,10,10,10},
  {10,10,10,10,10,10,10,10},
};

// Quant entries: (RN_f64(1/q), q) — constants fold into the unrolled stream.
struct QE { double r; float q; float pad; };
struct QTabE { QE v[8][8]; };
static constexpr QTabE mkqe(const float (&b)[8][8]) {
  QTabE t{};
  for (int i = 0; i < 8; ++i)
    for (int j = 0; j < 8; ++j)
      t.v[i][j] = QE{1.0 / (double)b[i][j], b[i][j], 0.0f};
  return t;
}
static constexpr QTabE QLe = mkqe(QLt);
static constexpr QTabE QCe = mkqe(QCt);

__device__ __forceinline__ void dct8(const float x[8], float u[8]) {
  #pragma unroll
  for (int k = 0; k < 8; ++k) {
    float a = D8[k][0] * x[0];
    #pragma unroll
    for (int j = 1; j < 8; ++j) a += D8[k][j] * x[j];
    u[k] = a;
  }
}
__device__ __forceinline__ void idct8(const float x[8], float u[8]) {
  #pragma unroll
  for (int j = 0; j < 8; ++j) {
    float a = x[0] * D8[0][j];
    #pragma unroll
    for (int m = 1; m < 8; ++m) a += x[m] * D8[m][j];
    u[j] = a;
  }
}

// Branchless bit-exact RN_f32(x / RN_f32(1/255)) via f64 reciprocal multiply
// (error 2^-44 << 2^-39 margin to any f32 rounding midpoint).
__device__ __forceinline__ float to255(float x) {
  constexpr double R = 1.0 / (double)(1.0f / 255.0f);
  float q = (float)((double)x * R);
  return fminf(fmaxf(floorf(q), 0.0f), 255.0f);
}

// Branchless bit-exact round(RN_f32(u/q)) for integer q in [1,12].
__device__ __forceinline__ float quant_rt(float u, const QE& e) {
  float t = (float)((double)u * e.r);
  return rintf(t) * e.q;
}

// Full 8x8 JPEG DCT roundtrip, entirely in registers (constant indexing).
// Accumulation orders identical to the R5 LDS version -> bit-identical out.
__device__ __forceinline__ void dct_block(float (&y)[64], const QTabE& Q) {
  float t[8], u[8];
  #pragma unroll
  for (int i = 0; i < 8; ++i) {            // row DCT (in place)
    #pragma unroll
    for (int j = 0; j < 8; ++j) t[j] = y[i*8+j];
    dct8(t, u);
    #pragma unroll
    for (int j = 0; j < 8; ++j) y[i*8+j] = u[j];
  }
  #pragma unroll
  for (int b = 0; b < 8; ++b) {            // col DCT + quant + col IDCT
    #pragma unroll
    for (int i = 0; i < 8; ++i) t[i] = y[i*8+b];
    dct8(t, u);
    #pragma unroll
    for (int m = 0; m < 8; ++m) u[m] = quant_rt(u[m], Q.v[m][b]);
    idct8(u, t);
    #pragma unroll
    for (int i = 0; i < 8; ++i) y[i*8+b] = t[i];
  }
  #pragma unroll
  for (int i = 0; i < 8; ++i) {            // row IDCT (in place)
    #pragma unroll
    for (int j = 0; j < 8; ++j) t[j] = y[i*8+j];
    idct8(t, u);
    #pragma unroll
    for (int j = 0; j < 8; ++j) y[i*8+j] = u[j];
  }
}

// One lane = one 8x8 luma block, register-resident end-to-end. Wave64 covers
// a 128x32 px tile (16 block-cols x 4 block-rows = 16 macroblocks). LDS only
// carries the 4:2:0 chroma coupling: 4x4 downsampled patches in, recon out.
// Lanes 0..31 each own one 8x8 chroma block (16 Cb + 16 Cr), also register-
// resident. Wave-autonomous: zero barriers (in-order DS pipe orders the
// write->read handoffs within the wave).
// LDS: Cb patches @0, Cr @1152; macroblock stride 72 (pad kills pow2 stride).
__global__ __launch_bounds__(64, 2) void jpeg_rt(const float* __restrict__ in,
                                                 float* __restrict__ out)
{
  __shared__ __align__(16) float CH[2304];

  const int l   = threadIdx.x;  // lane 0..63
  const int tx  = blockIdx.x;   // 0..3  (128-col band)
  const int ty  = blockIdx.y;   // 0..15 (32-row band)
  const int img = blockIdx.z;   // 0..31

  const int bc = l & 15, br = l >> 4;
  const int row0 = ty*32 + br*8;
  const int col0 = tx*128 + bc*8;
  const int mbi = (br >> 1)*8 + (bc >> 1);   // macroblock 0..15
  const int qr  = br & 1, qc = bc & 1;       // quadrant in macroblock

  const float* gbase = in + ((size_t)(img*512 + row0)*512 + col0)*3;

  float y[64];

  // ---------------- phase 1: load 8x8x3, convert, Y->regs, patches->LDS
  {
    float cbA[8], crA[8];
    #pragma unroll
    for (int rp = 0; rp < 4; ++rp) {
      #pragma unroll
      for (int h = 0; h < 2; ++h) {
        const int r = rp*2 + h;
        const float* rpx = gbase + (size_t)r*1536;
        float4 L0 = ((const float4*)rpx)[0];
        float4 L1 = ((const float4*)rpx)[1];
        float4 L2 = ((const float4*)rpx)[2];
        float4 L3 = ((const float4*)rpx)[3];
        float4 L4 = ((const float4*)rpx)[4];
        float4 L5 = ((const float4*)rpx)[5];
        float px[24] = {L0.x,L0.y,L0.z,L0.w, L1.x,L1.y,L1.z,L1.w,
                        L2.x,L2.y,L2.z,L2.w, L3.x,L3.y,L3.z,L3.w,
                        L4.x,L4.y,L4.z,L4.w, L5.x,L5.y,L5.z,L5.w};
        float cbr[8], crr[8];
        #pragma unroll
        for (int p = 0; p < 8; ++p) {
          float R = to255(px[3*p+0]);
          float G = to255(px[3*p+1]);
          float B = to255(px[3*p+2]);
          float Y = 0.299f*R + 0.587f*G + 0.114f*B;
          y[r*8+p] = Y - 128.0f;
          cbr[p] = -0.168736f*R - 0.331264f*G + 0.5f*B + 128.0f;
          crr[p] =  0.5f*R - 0.418688f*G - 0.081312f*B + 128.0f;
        }
        if (h == 0) {
          #pragma unroll
          for (int p = 0; p < 8; ++p) { cbA[p] = cbr[p]; crA[p] = crr[p]; }
        } else {
          float pb[4], pr2[4];
          #pragma unroll
          for (int c = 0; c < 4; ++c) {
            pb[c]  = ((cbA[2*c]+cbA[2*c+1]) + (cbr[2*c]+cbr[2*c+1]))*0.25f - 128.0f;
            pr2[c] = ((crA[2*c]+crA[2*c+1]) + (crr[2*c]+crr[2*c+1]))*0.25f - 128.0f;
          }
          *(float4*)&CH[       mbi*72 + (qr*4+rp)*8 + qc*4] = make_float4(pb[0],pb[1],pb[2],pb[3]);
          *(float4*)&CH[1152 + mbi*72 + (qr*4+rp)*8 + qc*4] = make_float4(pr2[0],pr2[1],pr2[2],pr2[3]);
        }
      }
    }
  }

  // ---------------- phase 2: luma DCT roundtrip, all in registers
  dct_block(y, QLe);

  // ---------------- phase 3: chroma blocks (lanes 0..31), register-resident
  if (l < 32) {
    const int ch = l >> 4;        // 0 = Cb, 1 = Cr
    const int mb = l & 15;
    const int cbase = ch*1152 + mb*72;
    float c[64];
    #pragma unroll
    for (int k = 0; k < 8; ++k) {
      *(float4*)&c[k*8+0] = *(const float4*)&CH[cbase + k*8 + 0];
      *(float4*)&c[k*8+4] = *(const float4*)&CH[cbase + k*8 + 4];
    }
    dct_block(c, QCe);
    #pragma unroll
    for (int k = 0; k < 8; ++k) {
      *(float4*)&CH[cbase + k*8 + 0] = *(const float4*)&c[k*8+0];
      *(float4*)&CH[cbase + k*8 + 4] = *(const float4*)&c[k*8+4];
    }
  }

  // ---------------- phase 4: upsample, YCbCr->RGB, round/clip, *(1/255)
  {
    const float c255 = (float)(1.0 / 255.0);  // <=1 ulp vs true div
    float* obase = out + ((size_t)(img*512 + row0)*512 + col0)*3;
    #pragma unroll
    for (int k = 0; k < 4; ++k) {
      float4 cb4 = *(const float4*)&CH[       mbi*72 + (qr*4+k)*8 + qc*4];
      float4 cr4 = *(const float4*)&CH[1152 + mbi*72 + (qr*4+k)*8 + qc*4];
      float cbq[4] = {cb4.x, cb4.y, cb4.z, cb4.w};
      float crq[4] = {cr4.x, cr4.y, cr4.z, cr4.w};
      #pragma unroll
      for (int h = 0; h < 2; ++h) {
        const int r = 2*k + h;
        float ov[24];
        #pragma unroll
        for (int p = 0; p < 8; ++p) {
          float y2  = y[r*8+p] + 128.0f;
          float cb2 = cbq[p>>1] + 128.0f;
          float cr2 = crq[p>>1] + 128.0f;
          float r2 = y2 + 1.402f*(cr2 - 128.0f);
          float g2 = y2 - 0.344136f*(cb2 - 128.0f) - 0.714136f*(cr2 - 128.0f);
          float b2 = y2 + 1.772f*(cb2 - 128.0f);
          ov[3*p+0] = rintf(fminf(fmaxf(r2, 0.0f), 255.0f)) * c255;
          ov[3*p+1] = rintf(fminf(fmaxf(g2, 0.0f), 255.0f)) * c255;
          ov[3*p+2] = rintf(fminf(fmaxf(b2, 0.0f), 255.0f)) * c255;
        }
        float* op = obase + (size_t)r*1536;
        ((float4*)op)[0] = make_float4(ov[0], ov[1], ov[2], ov[3]);
        ((float4*)op)[1] = make_float4(ov[4], ov[5], ov[6], ov[7]);
        ((float4*)op)[2] = make_float4(ov[8], ov[9], ov[10], ov[11]);
        ((float4*)op)[3] = make_float4(ov[12],ov[13],ov[14],ov[15]);
        ((float4*)op)[4] = make_float4(ov[16],ov[17],ov[18],ov[19]);
        ((float4*)op)[5] = make_float4(ov[20],ov[21],ov[22],ov[23]);
      }
    }
  }
}

extern "C" void kernel_launch(void* const* d_in, const int* in_sizes, int n_in,
                              void* d_out, int out_size, void* d_ws, size_t ws_size,
                              hipStream_t stream) {
  (void)in_sizes; (void)n_in; (void)d_ws; (void)ws_size; (void)out_size;
  const float* x = (const float*)d_in[0];
  float* out = (float*)d_out;
  dim3 grid(4, 16, 32);   // W/128, H/32, B
  jpeg_rt<<<grid, dim3(64), 0, stream>>>(x, out);
}